// Round 1
// baseline (1060.484 us; speedup 1.0000x reference)
//
#include <hip/hip_runtime.h>
#include <math.h>

#define N_ROWS 65536
#define KCODES 8192
#define DIM 64

// workspace layout (in floats)
#define WS_WSQ   0          // 8192
#define WS_IDX   8192       // 65536 ints
#define WS_BINS  73728      // 8192
#define WS_ESUM  81920      // 524288
#define WS_LOSS  606208     // 1

// ---------------- kernel A: per-code squared norms ----------------
__global__ void wsq_kernel(const float* __restrict__ w, float* __restrict__ wsq) {
    int wid = (blockIdx.x * blockDim.x + threadIdx.x) >> 6;
    int lane = threadIdx.x & 63;
    if (wid >= KCODES) return;
    float v = w[(size_t)wid * DIM + lane];
    float s = v * v;
    #pragma unroll
    for (int off = 32; off > 0; off >>= 1) s += __shfl_xor(s, off);
    if (lane == 0) wsq[wid] = s;
}

// ---------------- kernel B: normalize z + argmin over codes ----------------
#define BM 128
#define BK 64
#define LDZ (BM + 4)   // 132: b128-aligned (132%4==0), banks rotate with d
#define LDW (BK + 4)   // 68

__launch_bounds__(256, 2)
__global__ void argmin_kernel(const float* __restrict__ z,
                              const float* __restrict__ w,
                              const float* __restrict__ wsq_g,
                              int* __restrict__ idx_ws,
                              float* __restrict__ idx_out) {
    __shared__ float zt[DIM * LDZ];     // zt[d][r], transposed, padded
    __shared__ float wt[DIM * LDW];     // wt[d][c], transposed, padded
    __shared__ float zsq_s[BM];
    __shared__ float wsq_s[BK];

    const int tid = threadIdx.x;
    const int lane = tid & 63;
    const int wv = tid >> 6;
    const int row0 = blockIdx.x * BM;

    // stage + l2-normalize z tile (wave per row)
    for (int r = wv; r < BM; r += 4) {
        float v = z[(size_t)(row0 + r) * DIM + lane];
        float s = v * v;
        #pragma unroll
        for (int off = 32; off > 0; off >>= 1) s += __shfl_xor(s, off);
        float zn = v / fmaxf(sqrtf(s), 1e-12f);   // exact div to match reference rounding
        float q = zn * zn;
        #pragma unroll
        for (int off = 32; off > 0; off >>= 1) q += __shfl_xor(q, off);
        zt[lane * LDZ + r] = zn;
        if (lane == 0) zsq_s[r] = q;
    }
    __syncthreads();

    const int tx = tid & 7;     // 8 code-groups of 8 codes
    const int ty = tid >> 3;    // 32 row-groups of 4 rows
    const int r0 = ty * 4;
    const int c0 = tx * 8;

    float zsqr[4];
    #pragma unroll
    for (int i = 0; i < 4; ++i) zsqr[i] = zsq_s[r0 + i];

    float dmin[4];
    int   kmin[4];
    #pragma unroll
    for (int i = 0; i < 4; ++i) { dmin[i] = 3.4e38f; kmin[i] = 0; }

    const int c_ld  = tid >> 2;        // 0..63 : code within tile
    const int d0_ld = (tid & 3) * 16;  // 0,16,32,48 : dim quarter

    for (int t = 0; t < KCODES / BK; ++t) {
        __syncthreads();
        // stage weight tile, transposed into LDS
        {
            const float* src = &w[(size_t)(t * BK + c_ld) * DIM + d0_ld];
            #pragma unroll
            for (int j = 0; j < 16; j += 4) {
                float4 v4 = *(const float4*)(src + j);
                wt[(d0_ld + j + 0) * LDW + c_ld] = v4.x;
                wt[(d0_ld + j + 1) * LDW + c_ld] = v4.y;
                wt[(d0_ld + j + 2) * LDW + c_ld] = v4.z;
                wt[(d0_ld + j + 3) * LDW + c_ld] = v4.w;
            }
            if (tid < BK) wsq_s[tid] = wsq_g[t * BK + tid];
        }
        __syncthreads();

        float acc[4][8];
        #pragma unroll
        for (int i = 0; i < 4; ++i)
            #pragma unroll
            for (int j = 0; j < 8; ++j) acc[i][j] = 0.f;

        #pragma unroll 8
        for (int d = 0; d < DIM; ++d) {
            float4 zv = *(const float4*)&zt[d * LDZ + r0];
            float4 wa = *(const float4*)&wt[d * LDW + c0];
            float4 wb = *(const float4*)&wt[d * LDW + c0 + 4];
            float zr[4] = {zv.x, zv.y, zv.z, zv.w};
            float wr[8] = {wa.x, wa.y, wa.z, wa.w, wb.x, wb.y, wb.z, wb.w};
            #pragma unroll
            for (int i = 0; i < 4; ++i)
                #pragma unroll
                for (int j = 0; j < 8; ++j)
                    acc[i][j] = fmaf(zr[i], wr[j], acc[i][j]);
        }

        // d = (|z|^2 - 2*dot) + |w|^2, first-occurrence argmin (codes ascending)
        #pragma unroll
        for (int j = 0; j < 8; ++j) {
            int c = t * BK + c0 + j;
            float wq = wsq_s[c0 + j];
            #pragma unroll
            for (int i = 0; i < 4; ++i) {
                float dist = (zsqr[i] - 2.0f * acc[i][j]) + wq;
                if (dist < dmin[i]) { dmin[i] = dist; kmin[i] = c; }
            }
        }
    }

    // reduce argmin across the 8 tx lanes sharing each row (tie-break: lower index)
    #pragma unroll
    for (int i = 0; i < 4; ++i) {
        float dv = dmin[i]; int kv = kmin[i];
        #pragma unroll
        for (int off = 1; off < 8; off <<= 1) {
            float d2 = __shfl_xor(dv, off);
            int   k2 = __shfl_xor(kv, off);
            if (d2 < dv || (d2 == dv && k2 < kv)) { dv = d2; kv = k2; }
        }
        if (tx == 0) {
            int row = row0 + r0 + i;
            idx_ws[row] = kv;
            idx_out[row] = (float)kv;
        }
    }
}

// ---------------- kernel C: gather z_q, loss partials, scatter EMA stats ----------------
__global__ void stats_kernel(const float* __restrict__ z,
                             const float* __restrict__ w,
                             const int* __restrict__ idx_ws,
                             float* __restrict__ zq_out,
                             float* __restrict__ bins,
                             float* __restrict__ esum,
                             float* __restrict__ loss_acc) {
    const int lane = threadIdx.x & 63;
    const int wv = threadIdx.x >> 6;
    const int gw = blockIdx.x * 4 + wv;
    const int nw = gridDim.x * 4;
    float lsum = 0.f;
    for (int row = gw; row < N_ROWS; row += nw) {
        float v = z[(size_t)row * DIM + lane];
        float s = v * v;
        #pragma unroll
        for (int off = 32; off > 0; off >>= 1) s += __shfl_xor(s, off);
        float zn = v / fmaxf(sqrtf(s), 1e-12f);
        int k = idx_ws[row];
        float wq = w[(size_t)k * DIM + lane];
        zq_out[(size_t)row * DIM + lane] = wq;          // z + sg(z_q - z) == z_q
        float diff = wq - zn;
        lsum += diff * diff;
        atomicAdd(&esum[(size_t)k * DIM + lane], zn);
        if (lane == 0) atomicAdd(&bins[k], 1.0f);
    }
    __shared__ float red[256];
    red[threadIdx.x] = lsum;
    __syncthreads();
    for (int s = 128; s > 0; s >>= 1) {
        if (threadIdx.x < s) red[threadIdx.x] += red[threadIdx.x + s];
        __syncthreads();
    }
    if (threadIdx.x == 0) atomicAdd(loss_acc, red[0]);
}

// ---------------- kernel D: per-code EMA finalize + loss scalar ----------------
__global__ void finalize_kernel(const float* __restrict__ w,
                                const float* __restrict__ cs,
                                const float* __restrict__ ea,
                                const float* __restrict__ bins,
                                const float* __restrict__ esum,
                                const float* __restrict__ loss_acc,
                                float* __restrict__ out_cs,
                                float* __restrict__ out_ea,
                                float* __restrict__ out_w,
                                float* __restrict__ out_loss) {
    const int gid = blockIdx.x * blockDim.x + threadIdx.x;
    if (gid == 0) out_loss[0] = 0.25f * loss_acc[0] / 4194304.0f;  // BETA * mean
    const int k = gid >> 6;
    const int lane = threadIdx.x & 63;
    if (k >= KCODES) return;
    float b = bins[k];
    if (lane == 0) out_cs[k] = cs[k] * 0.99f + 0.01f * b;
    size_t off = (size_t)k * DIM + lane;
    float es = esum[off];
    out_ea[off] = ea[off] * 0.99f + 0.01f * es;
    float wv = w[off];
    float bc = (b == 0.0f) ? 1.0f : b;
    float t = es / bc;
    float s = t * t;
    #pragma unroll
    for (int o = 32; o > 0; o >>= 1) s += __shfl_xor(s, o);
    float en = t / fmaxf(sqrtf(s), 1e-12f);
    if (b == 0.0f) en = wv;                        // dead code keeps old weight
    float nw = wv * 0.99f + 0.01f * en;
    float s2 = nw * nw;
    #pragma unroll
    for (int o = 32; o > 0; o >>= 1) s2 += __shfl_xor(s2, o);
    out_w[off] = nw / fmaxf(sqrtf(s2), 1e-12f);
}

extern "C" void kernel_launch(void* const* d_in, const int* in_sizes, int n_in,
                              void* d_out, int out_size, void* d_ws, size_t ws_size,
                              hipStream_t stream) {
    const float* z  = (const float*)d_in[0];
    const float* w  = (const float*)d_in[1];
    const float* cs = (const float*)d_in[2];
    const float* ea = (const float*)d_in[3];

    float* out = (float*)d_out;
    float* out_zq   = out;                 // 4194304
    float* out_loss = out + 4194304;       // 1
    float* out_idx  = out + 4194305;       // 65536
    float* out_cs   = out + 4259841;       // 8192
    float* out_ea   = out + 4268033;       // 524288
    float* out_w    = out + 4792321;       // 524288

    float* ws = (float*)d_ws;
    float* wsq  = ws + WS_WSQ;
    int*   idxb = (int*)(ws + WS_IDX);
    float* bins = ws + WS_BINS;
    float* esum = ws + WS_ESUM;
    float* loss = ws + WS_LOSS;

    // zero bins + embed_sum + loss (contiguous region); ws is poisoned 0xAA pre-launch
    hipMemsetAsync(bins, 0, (size_t)(8192 + 524288 + 1) * sizeof(float), stream);

    wsq_kernel<<<KCODES * 64 / 256, 256, 0, stream>>>(w, wsq);
    argmin_kernel<<<N_ROWS / BM, 256, 0, stream>>>(z, w, wsq, idxb, out_idx);
    stats_kernel<<<512, 256, 0, stream>>>(z, w, idxb, out_zq, bins, esum, loss);
    finalize_kernel<<<KCODES * 64 / 256, 256, 0, stream>>>(w, cs, ea, bins, esum, loss,
                                                           out_cs, out_ea, out_w, out_loss);
}

// Round 2
// 613.667 us; speedup vs baseline: 1.7281x; 1.7281x over previous
//
#include <hip/hip_runtime.h>
#include <math.h>

#define N_ROWS 65536
#define KCODES 8192
#define DIM 64
#define MARGIN 1e-3f

// workspace layout (floats) -- same proven footprint as round 1
#define WS_WSQ   0          // 8192
#define WS_IDX   8192       // 65536 ints
#define WS_BINS  73728      // 8192
#define WS_ESUM  81920      // 524288
#define WS_LOSS  606208     // 1

// d_out scratch (inside z_q region, overwritten later by stats_kernel):
//   whl (bf16 hi/lo split of w): ushort[8192*128]  = floats [0, 524288)
//   count: int at float offset 524288
//   list:  int[65536] at float offset 524289

typedef short short8 __attribute__((ext_vector_type(8)));
typedef float f32x4 __attribute__((ext_vector_type(4)));

#define MFMA_BF16(A, B, C) __builtin_amdgcn_mfma_f32_16x16x32_bf16(A, B, C, 0, 0, 0)

__device__ inline unsigned short f2bf(float f) {
    unsigned u = __float_as_uint(f);
    unsigned r = u + 0x7FFFu + ((u >> 16) & 1u);   // RTNE
    return (unsigned short)(r >> 16);
}
__device__ inline float b2f(unsigned short h) {
    return __uint_as_float(((unsigned)h) << 16);
}

// ---------------- kernel A: per-code squared norms + bf16 hi/lo split ----------------
__global__ void prep_kernel(const float* __restrict__ w, float* __restrict__ wsq,
                            unsigned short* __restrict__ whl) {
    int wid = (blockIdx.x * blockDim.x + threadIdx.x) >> 6;
    int lane = threadIdx.x & 63;
    if (wid >= KCODES) return;
    float v = w[(size_t)wid * DIM + lane];
    float s = v * v;
    #pragma unroll
    for (int off = 32; off > 0; off >>= 1) s += __shfl_xor(s, off);
    if (lane == 0) wsq[wid] = s;
    unsigned short h = f2bf(v);
    unsigned short l = f2bf(v - b2f(h));
    whl[(size_t)wid * 128 + lane] = h;
    whl[(size_t)wid * 128 + 64 + lane] = l;
}

// ---------------- kernel B: MFMA argmax-dot with top-2 margin flagging ----------------
// 256 blocks x 256 thr. BM=256 rows/block (wave owns 64 rows = 4 mtiles of 16).
// K-sweep over codes in rounds of BN=64 (4 ntiles of 16), B staged in LDS.
__launch_bounds__(256, 1)
__global__ void argmin_mfma_kernel(const float* __restrict__ z,
                                   const unsigned short* __restrict__ whl,
                                   int* __restrict__ idx_ws,
                                   float* __restrict__ idx_out,
                                   int* __restrict__ countp,
                                   int* __restrict__ list) {
    // LDS: prologue uses zAh/zAl (256x72 ushort each = 73728 B);
    // main loop reuses the same region for the B tile (64x72 hi + 64x72 lo).
    __shared__ unsigned short smem[36864];
    unsigned short* zAh = smem;
    unsigned short* zAl = smem + 18432;
    unsigned short* whS = smem;          // reused after A-frag extraction
    unsigned short* wlS = smem + 4608;

    const int tid = threadIdx.x;
    const int lane = tid & 63;
    const int wv = tid >> 6;
    const int n_a = lane & 15;
    const int quad = lane >> 4;
    const int row0 = blockIdx.x * 256;

    // ---- prologue: normalize 256 z rows, split to bf16 hi/lo in LDS ----
    for (int rr = 0; rr < 64; ++rr) {
        int row = wv * 64 + rr;
        float v = z[(size_t)(row0 + row) * DIM + lane];
        float s = v * v;
        #pragma unroll
        for (int off = 32; off > 0; off >>= 1) s += __shfl_xor(s, off);
        float zn = v / fmaxf(sqrtf(s), 1e-12f);
        unsigned short h = f2bf(zn);
        unsigned short l = f2bf(zn - b2f(h));
        zAh[row * 72 + lane] = h;
        zAl[row * 72 + lane] = l;
    }
    __syncthreads();

    // ---- extract A fragments to registers (held for whole kernel) ----
    // A layout (16x16x32): A[m = lane&15][k = quad*8 + j]
    short8 a_h[4][2], a_l[4][2];
    #pragma unroll
    for (int mt = 0; mt < 4; ++mt) {
        int m = wv * 64 + mt * 16 + n_a;
        #pragma unroll
        for (int ks = 0; ks < 2; ++ks) {
            a_h[mt][ks] = *(const short8*)(zAh + m * 72 + ks * 32 + quad * 8);
            a_l[mt][ks] = *(const short8*)(zAl + m * 72 + ks * 32 + quad * 8);
        }
    }
    __syncthreads();

    // running top-2 per tracked row: 4 mtiles x 4 regs
    float m1[4][4], m2[4][4];
    int kk[4][4];
    #pragma unroll
    for (int mt = 0; mt < 4; ++mt)
        #pragma unroll
        for (int i = 0; i < 4; ++i) { m1[mt][i] = -3.4e38f; m2[mt][i] = -3.4e38f; kk[mt][i] = 0; }

    // B staging: thread t copies 64B segment: code c_ld = t>>2, seg = t&3
    const int c_ld = tid >> 2;
    const int seg = tid & 3;
    unsigned short* dstS = ((seg < 2) ? whS : wlS) + c_ld * 72 + (seg & 1) * 32;

    int4 pf0, pf1, pf2, pf3;
    {
        const int4* gsrc = (const int4*)(whl + (size_t)c_ld * 128 + seg * 32);
        pf0 = gsrc[0]; pf1 = gsrc[1]; pf2 = gsrc[2]; pf3 = gsrc[3];
    }

    for (int r = 0; r < KCODES / 64; ++r) {
        // commit prefetched tile to LDS
        ((int4*)dstS)[0] = pf0; ((int4*)dstS)[1] = pf1;
        ((int4*)dstS)[2] = pf2; ((int4*)dstS)[3] = pf3;
        __syncthreads();
        if (r + 1 < KCODES / 64) {
            const int4* gsrc = (const int4*)(whl + ((size_t)(r + 1) * 64 + c_ld) * 128 + seg * 32);
            pf0 = gsrc[0]; pf1 = gsrc[1]; pf2 = gsrc[2]; pf3 = gsrc[3];
        }

        const int cbase = r * 64;
        short8 bh[2][2], bl[2][2];
        f32x4 acc[2][4];

        // load B frags ntile 0, compute into acc[0]
        {
            int base = n_a * 72 + quad * 8;
            bh[0][0] = *(const short8*)(whS + base);
            bh[0][1] = *(const short8*)(whS + base + 32);
            bl[0][0] = *(const short8*)(wlS + base);
            bl[0][1] = *(const short8*)(wlS + base + 32);
            #pragma unroll
            for (int mt = 0; mt < 4; ++mt) {
                f32x4 a = {0.f, 0.f, 0.f, 0.f};
                a = MFMA_BF16(a_h[mt][0], bh[0][0], a);
                a = MFMA_BF16(a_h[mt][1], bh[0][1], a);
                a = MFMA_BF16(a_l[mt][0], bh[0][0], a);
                a = MFMA_BF16(a_l[mt][1], bh[0][1], a);
                a = MFMA_BF16(a_h[mt][0], bl[0][0], a);
                a = MFMA_BF16(a_h[mt][1], bl[0][1], a);
                acc[0][mt] = a;
            }
        }

        #pragma unroll
        for (int nt = 0; nt < 4; ++nt) {
            const int p = nt & 1, q = p ^ 1;
            if (nt < 3) {   // issue next ntile's MFMAs before this epilogue (overlap)
                int base = ((nt + 1) * 16 + n_a) * 72 + quad * 8;
                bh[q][0] = *(const short8*)(whS + base);
                bh[q][1] = *(const short8*)(whS + base + 32);
                bl[q][0] = *(const short8*)(wlS + base);
                bl[q][1] = *(const short8*)(wlS + base + 32);
                #pragma unroll
                for (int mt = 0; mt < 4; ++mt) {
                    f32x4 a = {0.f, 0.f, 0.f, 0.f};
                    a = MFMA_BF16(a_h[mt][0], bh[q][0], a);
                    a = MFMA_BF16(a_h[mt][1], bh[q][1], a);
                    a = MFMA_BF16(a_l[mt][0], bh[q][0], a);
                    a = MFMA_BF16(a_l[mt][1], bh[q][1], a);
                    a = MFMA_BF16(a_h[mt][0], bl[q][0], a);
                    a = MFMA_BF16(a_h[mt][1], bl[q][1], a);
                    acc[q][mt] = a;
                }
            }
            // epilogue: top-2 tracking (maximize dot)
            const int c = cbase + nt * 16 + n_a;
            #pragma unroll
            for (int mt = 0; mt < 4; ++mt)
                #pragma unroll
                for (int i = 0; i < 4; ++i) {
                    float v = acc[p][mt][i];
                    float t = fminf(v, m1[mt][i]);
                    bool gt = v > m1[mt][i];
                    kk[mt][i] = gt ? c : kk[mt][i];
                    m1[mt][i] = fmaxf(m1[mt][i], v);
                    m2[mt][i] = fmaxf(m2[mt][i], t);
                }
        }
        __syncthreads();
    }

    // ---- reduce top-2 across the 16 col-lanes per row; write winners; flag close rows ----
    #pragma unroll
    for (int mt = 0; mt < 4; ++mt)
        #pragma unroll
        for (int i = 0; i < 4; ++i) {
            float v1 = m1[mt][i], v2 = m2[mt][i];
            int k = kk[mt][i];
            #pragma unroll
            for (int off = 1; off < 16; off <<= 1) {
                float o1 = __shfl_xor(v1, off);
                float o2 = __shfl_xor(v2, off);
                int ok = __shfl_xor(k, off);
                float lo = fminf(v1, o1);
                v2 = fmaxf(fmaxf(v2, o2), lo);
                bool take = (o1 > v1) || (o1 == v1 && ok < k);
                k = take ? ok : k;
                v1 = fmaxf(v1, o1);
            }
            if (n_a == 0) {
                int row_g = row0 + wv * 64 + mt * 16 + quad * 4 + i;
                idx_ws[row_g] = k;
                idx_out[row_g] = (float)k;
                if (v1 - v2 < MARGIN) {
                    int pos = atomicAdd(countp, 1);
                    list[pos] = row_g;
                }
            }
        }
}

// ---------------- kernel C: exact fp32 re-rank for margin-flagged rows ----------------
__global__ void fallback_kernel(const float* __restrict__ z,
                                const float* __restrict__ w,
                                const float* __restrict__ wsq,
                                const int* __restrict__ countp,
                                const int* __restrict__ list,
                                int* __restrict__ idx_ws,
                                float* __restrict__ idx_out) {
    __shared__ float znsm[16][64];
    __shared__ float zsqsm[16];
    __shared__ float wdist[4][16];
    __shared__ int wkidx[4][16];

    const int tid = threadIdx.x;
    const int lane = tid & 63;
    const int wv = tid >> 6;
    const int count = *countp;
    const int ngroups = (count + 15) / 16;

    for (int g = blockIdx.x; g < ngroups; g += gridDim.x) {
        const int nrows = min(16, count - g * 16);
        // stage 16 normalized rows (wave per 4 rows)
        #pragma unroll
        for (int j = 0; j < 4; ++j) {
            int ri = wv * 4 + j;
            if (ri < nrows) {
                int row = list[g * 16 + ri];
                float v = z[(size_t)row * DIM + lane];
                float s = v * v;
                #pragma unroll
                for (int off = 32; off > 0; off >>= 1) s += __shfl_xor(s, off);
                float zn = v / fmaxf(sqrtf(s), 1e-12f);
                float qq = zn * zn;
                #pragma unroll
                for (int off = 32; off > 0; off >>= 1) qq += __shfl_xor(qq, off);
                znsm[ri][lane] = zn;
                if (lane == 0) zsqsm[ri] = qq;
            }
        }
        __syncthreads();

        float dmin[16];
        int kmin[16];
        #pragma unroll
        for (int rr = 0; rr < 16; ++rr) { dmin[rr] = 3.4e38f; kmin[rr] = 0; }

        for (int ci = 0; ci < KCODES / 256; ++ci) {
            int c = ci * 256 + tid;   // ascending per thread -> first-occurrence within thread
            float acc[16];
            #pragma unroll
            for (int rr = 0; rr < 16; ++rr) acc[rr] = 0.f;
            #pragma unroll 4
            for (int d4 = 0; d4 < 16; ++d4) {
                float4 wv4 = *(const float4*)&w[(size_t)c * DIM + d4 * 4];
                #pragma unroll
                for (int rr = 0; rr < 16; ++rr) {
                    acc[rr] = fmaf(wv4.x, znsm[rr][d4 * 4 + 0], acc[rr]);
                    acc[rr] = fmaf(wv4.y, znsm[rr][d4 * 4 + 1], acc[rr]);
                    acc[rr] = fmaf(wv4.z, znsm[rr][d4 * 4 + 2], acc[rr]);
                    acc[rr] = fmaf(wv4.w, znsm[rr][d4 * 4 + 3], acc[rr]);
                }
            }
            float wq = wsq[c];
            #pragma unroll
            for (int rr = 0; rr < 16; ++rr) {
                float dist = (zsqsm[rr] - 2.0f * acc[rr]) + wq;
                if (dist < dmin[rr]) { dmin[rr] = dist; kmin[rr] = c; }
            }
        }

        // per-wave shuffle reduce, then cross-wave merge
        #pragma unroll
        for (int rr = 0; rr < 16; ++rr) {
            float dv = dmin[rr]; int kv = kmin[rr];
            #pragma unroll
            for (int off = 1; off < 64; off <<= 1) {
                float d2 = __shfl_xor(dv, off);
                int k2 = __shfl_xor(kv, off);
                if (d2 < dv || (d2 == dv && k2 < kv)) { dv = d2; kv = k2; }
            }
            if (lane == 0) { wdist[wv][rr] = dv; wkidx[wv][rr] = kv; }
        }
        __syncthreads();
        if (tid < 16 && tid < nrows) {
            float dv = wdist[0][tid]; int kv = wkidx[0][tid];
            #pragma unroll
            for (int wvi = 1; wvi < 4; ++wvi) {
                float d2 = wdist[wvi][tid]; int k2 = wkidx[wvi][tid];
                if (d2 < dv || (d2 == dv && k2 < kv)) { dv = d2; kv = k2; }
            }
            int row = list[g * 16 + tid];
            idx_ws[row] = kv;
            idx_out[row] = (float)kv;
        }
        __syncthreads();
    }
}

// ---------------- kernel D: gather z_q, loss partials, scatter EMA stats ----------------
__global__ void stats_kernel(const float* __restrict__ z,
                             const float* __restrict__ w,
                             const int* __restrict__ idx_ws,
                             float* __restrict__ zq_out,
                             float* __restrict__ bins,
                             float* __restrict__ esum,
                             float* __restrict__ loss_acc) {
    const int lane = threadIdx.x & 63;
    const int wv = threadIdx.x >> 6;
    const int gw = blockIdx.x * 4 + wv;
    const int nw = gridDim.x * 4;
    float lsum = 0.f;
    for (int row = gw; row < N_ROWS; row += nw) {
        float v = z[(size_t)row * DIM + lane];
        float s = v * v;
        #pragma unroll
        for (int off = 32; off > 0; off >>= 1) s += __shfl_xor(s, off);
        float zn = v / fmaxf(sqrtf(s), 1e-12f);
        int k = idx_ws[row];
        float wq = w[(size_t)k * DIM + lane];
        zq_out[(size_t)row * DIM + lane] = wq;
        float diff = wq - zn;
        lsum += diff * diff;
        atomicAdd(&esum[(size_t)k * DIM + lane], zn);
        if (lane == 0) atomicAdd(&bins[k], 1.0f);
    }
    __shared__ float red[256];
    red[threadIdx.x] = lsum;
    __syncthreads();
    for (int s = 128; s > 0; s >>= 1) {
        if (threadIdx.x < s) red[threadIdx.x] += red[threadIdx.x + s];
        __syncthreads();
    }
    if (threadIdx.x == 0) atomicAdd(loss_acc, red[0]);
}

// ---------------- kernel E: per-code EMA finalize + loss scalar ----------------
__global__ void finalize_kernel(const float* __restrict__ w,
                                const float* __restrict__ cs,
                                const float* __restrict__ ea,
                                const float* __restrict__ bins,
                                const float* __restrict__ esum,
                                const float* __restrict__ loss_acc,
                                float* __restrict__ out_cs,
                                float* __restrict__ out_ea,
                                float* __restrict__ out_w,
                                float* __restrict__ out_loss) {
    const int gid = blockIdx.x * blockDim.x + threadIdx.x;
    if (gid == 0) out_loss[0] = 0.25f * loss_acc[0] / 4194304.0f;
    const int k = gid >> 6;
    const int lane = threadIdx.x & 63;
    if (k >= KCODES) return;
    float b = bins[k];
    if (lane == 0) out_cs[k] = cs[k] * 0.99f + 0.01f * b;
    size_t off = (size_t)k * DIM + lane;
    float es = esum[off];
    out_ea[off] = ea[off] * 0.99f + 0.01f * es;
    float wv = w[off];
    float bc = (b == 0.0f) ? 1.0f : b;
    float t = es / bc;
    float s = t * t;
    #pragma unroll
    for (int o = 32; o > 0; o >>= 1) s += __shfl_xor(s, o);
    float en = t / fmaxf(sqrtf(s), 1e-12f);
    if (b == 0.0f) en = wv;
    float nw = wv * 0.99f + 0.01f * en;
    float s2 = nw * nw;
    #pragma unroll
    for (int o = 32; o > 0; o >>= 1) s2 += __shfl_xor(s2, o);
    out_w[off] = nw / fmaxf(sqrtf(s2), 1e-12f);
}

extern "C" void kernel_launch(void* const* d_in, const int* in_sizes, int n_in,
                              void* d_out, int out_size, void* d_ws, size_t ws_size,
                              hipStream_t stream) {
    const float* z  = (const float*)d_in[0];
    const float* w  = (const float*)d_in[1];
    const float* cs = (const float*)d_in[2];
    const float* ea = (const float*)d_in[3];

    float* out = (float*)d_out;
    float* out_zq   = out;                 // 4194304
    float* out_loss = out + 4194304;       // 1
    float* out_idx  = out + 4194305;       // 65536
    float* out_cs   = out + 4259841;       // 8192
    float* out_ea   = out + 4268033;       // 524288
    float* out_w    = out + 4792321;       // 524288

    // scratch inside the z_q output region (stats_kernel rewrites it all later)
    unsigned short* whl = (unsigned short*)d_out;       // 8192*128 ushorts = floats [0,524288)
    int* countp = (int*)(out + 524288);
    int* list   = (int*)(out + 524289);

    float* ws = (float*)d_ws;
    float* wsq  = ws + WS_WSQ;
    int*   idxb = (int*)(ws + WS_IDX);
    float* bins = ws + WS_BINS;
    float* esum = ws + WS_ESUM;
    float* loss = ws + WS_LOSS;

    hipMemsetAsync(bins, 0, (size_t)(8192 + 524288 + 1) * sizeof(float), stream);
    hipMemsetAsync(countp, 0, sizeof(int), stream);

    prep_kernel<<<KCODES * 64 / 256, 256, 0, stream>>>(w, wsq, whl);
    argmin_mfma_kernel<<<N_ROWS / 256, 256, 0, stream>>>(z, whl, idxb, out_idx, countp, list);
    fallback_kernel<<<256, 256, 0, stream>>>(z, w, wsq, countp, list, idxb, out_idx);
    stats_kernel<<<512, 256, 0, stream>>>(z, w, idxb, out_zq, bins, esum, loss);
    finalize_kernel<<<KCODES * 64 / 256, 256, 0, stream>>>(w, cs, ea, bins, esum, loss,
                                                           out_cs, out_ea, out_w, out_loss);
}

// Round 3
// 488.860 us; speedup vs baseline: 2.1693x; 1.2553x over previous
//
#include <hip/hip_runtime.h>
#include <math.h>

#define N_ROWS 65536
#define KCODES 8192
#define DIM 64
#define MARGIN 3e-4f
#define KSPLIT 4
#define KPER (KCODES / KSPLIT)   // 2048
#define NROUNDS (KPER / 64)      // 32

// workspace layout (floats)
#define WS_WSQ   0          // 8192
#define WS_IDX   8192       // 65536 ints
#define WS_BINS  73728      // 8192
#define WS_ESUM  81920      // 524288
#define WS_LOSS  606208     // 1

// d_out scratch (inside z_q region, overwritten later by stats_kernel):
//   whl: ushort[8192*128] = floats [0, 524288)
//   count @ float 524288 ; list @ [524289, 589825)
//   pm1 @ [1048576, 1310720) ; pm2 @ [1310720, 1572864) ; pk1 @ [1572864, 1835008)

typedef short short8 __attribute__((ext_vector_type(8)));
typedef float f32x4 __attribute__((ext_vector_type(4)));

#define MFMA_BF16(A, B, C) __builtin_amdgcn_mfma_f32_16x16x32_bf16(A, B, C, 0, 0, 0)

__device__ __forceinline__ unsigned short f2bf(float f) {
    unsigned u = __float_as_uint(f);
    unsigned r = u + 0x7FFFu + ((u >> 16) & 1u);   // RTNE
    return (unsigned short)(r >> 16);
}
__device__ __forceinline__ float b2f(unsigned short h) {
    return __uint_as_float(((unsigned)h) << 16);
}
__device__ __forceinline__ void gload16(const unsigned short* g, unsigned short* l) {
    __builtin_amdgcn_global_load_lds(
        (const __attribute__((address_space(1))) unsigned int*)g,
        (__attribute__((address_space(3))) unsigned int*)l, 16, 0, 0);
}

// ---------------- kernel A: per-code squared norms + bf16 hi/lo split ----------------
__global__ void prep_kernel(const float* __restrict__ w, float* __restrict__ wsq,
                            unsigned short* __restrict__ whl) {
    int wid = (blockIdx.x * blockDim.x + threadIdx.x) >> 6;
    int lane = threadIdx.x & 63;
    if (wid >= KCODES) return;
    float v = w[(size_t)wid * DIM + lane];
    float s = v * v;
    #pragma unroll
    for (int off = 32; off > 0; off >>= 1) s += __shfl_xor(s, off);
    if (lane == 0) wsq[wid] = s;
    unsigned short h = f2bf(v);
    unsigned short l = f2bf(v - b2f(h));
    whl[(size_t)wid * 128 + lane] = h;
    whl[(size_t)wid * 128 + 64 + lane] = l;
}

// ---------------- kernel B: K-split MFMA argmax-dot, per-(row,kq) top-2 partials ----------------
// grid 1024 = 256 rowblocks x 4 k-quarters. Block 256 thr = 4 waves x 64 rows.
__launch_bounds__(256, 3)
__global__ void argmin_mfma_kernel(const float* __restrict__ z,
                                   const unsigned short* __restrict__ whl,
                                   float* __restrict__ pm1,
                                   float* __restrict__ pm2,
                                   int* __restrict__ pk1) {
    // [0,8192) buf0 ; [8192,16384) buf1 (ushorts; 16 KB each)
    // prologue reuse: zs_h @ [0, 9216), zs_l @ [9216, 18432)
    __shared__ unsigned short smem[18432];

    const int tid = threadIdx.x;
    const int lane = tid & 63;
    const int wv = tid >> 6;
    const int n_a = lane & 15;
    const int quad = lane >> 4;
    const int rowblk = blockIdx.x >> 2;
    const int kq = blockIdx.x & 3;
    const int kbase = kq * KPER;

    short8 a_h[4][2], a_l[4][2];

    // ---- prologue: normalize 256 z rows in 2 passes of 128, split to bf16 hi/lo ----
    #pragma unroll
    for (int p = 0; p < 2; ++p) {
        for (int i = 0; i < 32; ++i) {
            int rr = i * 4 + wv;
            int row = rowblk * 256 + p * 128 + rr;
            float v = z[(size_t)row * DIM + lane];
            float s = v * v;
            #pragma unroll
            for (int off = 32; off > 0; off >>= 1) s += __shfl_xor(s, off);
            float zn = v / fmaxf(sqrtf(s), 1e-12f);
            unsigned short h = f2bf(zn);
            unsigned short l = f2bf(zn - b2f(h));
            smem[rr * 72 + lane] = h;
            smem[9216 + rr * 72 + lane] = l;
        }
        __syncthreads();
        if ((wv >> 1) == p) {
            #pragma unroll
            for (int mt = 0; mt < 4; ++mt) {
                int rr = (wv & 1) * 64 + mt * 16 + n_a;
                #pragma unroll
                for (int ks = 0; ks < 2; ++ks) {
                    a_h[mt][ks] = *(const short8*)(smem + rr * 72 + ks * 32 + quad * 8);
                    a_l[mt][ks] = *(const short8*)(smem + 9216 + rr * 72 + ks * 32 + quad * 8);
                }
            }
        }
        __syncthreads();
    }

    float m1v[4][4], m2v[4][4];
    int kkv[4][4];
    #pragma unroll
    for (int mt = 0; mt < 4; ++mt)
        #pragma unroll
        for (int i = 0; i < 4; ++i) { m1v[mt][i] = -3.4e38f; m2v[mt][i] = -3.4e38f; kkv[mt][i] = 0; }

    // B tile staging: XOR-swizzled layout, contiguous in lane order for global_load_lds.
    // slot s=(c_local, j_phys): holds global segment j_glob = j_phys ^ (c_local & 15).
    #define ISSUE_TILE(r, bdst)                                                  \
        {                                                                        \
            const size_t cg0 = (size_t)(kbase + (r) * 64);                       \
            _Pragma("unroll")                                                    \
            for (int i = 0; i < 4; ++i) {                                        \
                int slot = wv * 256 + i * 64 + lane;                             \
                int cl = slot >> 4;                                              \
                int jg = (slot & 15) ^ (cl & 15);                                \
                gload16(whl + (cg0 + cl) * 128 + jg * 8,                         \
                        (bdst) + wv * 2048 + i * 512);                           \
            }                                                                    \
        }

    ISSUE_TILE(0, smem);
    __syncthreads();

    for (int r = 0; r < NROUNDS; ++r) {
        unsigned short* bc = smem + (r & 1) * 8192;
        if (r + 1 < NROUNDS) {
            unsigned short* bn = smem + ((r + 1) & 1) * 8192;
            ISSUE_TILE(r + 1, bn);
        }
        #pragma unroll
        for (int nt = 0; nt < 4; ++nt) {
            const int cl = nt * 16 + n_a;
            const unsigned short* bp = bc + cl * 128;
            short8 bh0 = *(const short8*)(bp + ((quad) ^ n_a) * 8);
            short8 bh1 = *(const short8*)(bp + ((4 + quad) ^ n_a) * 8);
            short8 bl0 = *(const short8*)(bp + ((8 + quad) ^ n_a) * 8);
            short8 bl1 = *(const short8*)(bp + ((12 + quad) ^ n_a) * 8);
            f32x4 acc[4];
            #pragma unroll
            for (int mt = 0; mt < 4; ++mt) {
                f32x4 a = {0.f, 0.f, 0.f, 0.f};
                a = MFMA_BF16(a_h[mt][0], bh0, a);
                a = MFMA_BF16(a_h[mt][1], bh1, a);
                a = MFMA_BF16(a_l[mt][0], bh0, a);
                a = MFMA_BF16(a_l[mt][1], bh1, a);
                a = MFMA_BF16(a_h[mt][0], bl0, a);
                a = MFMA_BF16(a_h[mt][1], bl1, a);
                acc[mt] = a;
            }
            const int c = kbase + r * 64 + nt * 16 + n_a;
            #pragma unroll
            for (int mt = 0; mt < 4; ++mt)
                #pragma unroll
                for (int i = 0; i < 4; ++i) {
                    float v = acc[mt][i];
                    m2v[mt][i] = __builtin_amdgcn_fmed3f(v, m1v[mt][i], m2v[mt][i]);
                    bool gt = v > m1v[mt][i];
                    kkv[mt][i] = gt ? c : kkv[mt][i];
                    m1v[mt][i] = fmaxf(m1v[mt][i], v);
                }
        }
        __syncthreads();
    }

    // reduce top-2 across 16 col-lanes per row; write per-(row,kq) partials
    #pragma unroll
    for (int mt = 0; mt < 4; ++mt)
        #pragma unroll
        for (int i = 0; i < 4; ++i) {
            float v1 = m1v[mt][i], v2 = m2v[mt][i];
            int k = kkv[mt][i];
            #pragma unroll
            for (int off = 1; off < 16; off <<= 1) {
                float o1 = __shfl_xor(v1, off);
                float o2 = __shfl_xor(v2, off);
                int ok = __shfl_xor(k, off);
                float lo = fminf(v1, o1);
                v2 = fmaxf(fmaxf(v2, o2), lo);
                bool take = (o1 > v1) || (o1 == v1 && ok < k);
                k = take ? ok : k;
                v1 = fmaxf(v1, o1);
            }
            if (n_a == 0) {
                int row_g = rowblk * 256 + wv * 64 + mt * 16 + quad * 4 + i;
                int sl = row_g * 4 + kq;
                pm1[sl] = v1;
                pm2[sl] = v2;
                pk1[sl] = k;
            }
        }
}

// ---------------- kernel C: merge 4 K-partials per row, flag close rows ----------------
__global__ void merge_kernel(const float* __restrict__ pm1, const float* __restrict__ pm2,
                             const int* __restrict__ pk1,
                             int* __restrict__ idx_ws, float* __restrict__ idx_out,
                             int* __restrict__ countp, int* __restrict__ list) {
    int row = blockIdx.x * blockDim.x + threadIdx.x;
    if (row >= N_ROWS) return;
    float v1 = -3.4e38f, v2 = -3.4e38f;
    int k1 = 0x7fffffff;
    #pragma unroll
    for (int kq = 0; kq < KSPLIT; ++kq) {
        float a1 = pm1[row * 4 + kq];
        float a2 = pm2[row * 4 + kq];
        int ak = pk1[row * 4 + kq];
        if (a1 > v1) { v2 = v1; v1 = a1; k1 = ak; }
        else { v2 = fmaxf(v2, a1); if (a1 == v1 && ak < k1) k1 = ak; }
        v2 = fmaxf(v2, a2);
    }
    idx_ws[row] = k1;
    idx_out[row] = (float)k1;
    if (v1 - v2 < MARGIN) {
        int pos = atomicAdd(countp, 1);
        list[pos] = row;
    }
}

// ---------------- kernel D: exact fp32 re-rank, one wave per flagged row ----------------
__launch_bounds__(256, 2)
__global__ void fallback_kernel(const float* __restrict__ z, const float* __restrict__ w,
                                const float* __restrict__ wsq,
                                const int* __restrict__ countp, const int* __restrict__ list,
                                int* __restrict__ idx_ws, float* __restrict__ idx_out) {
    __shared__ float wt[64 * 68];
    const int tid = threadIdx.x;
    const int lane = tid & 63;
    const int wv = tid >> 6;
    const int count = *countp;
    const int ngroups = (count + 3) / 4;

    for (int g = blockIdx.x; g < ngroups; g += gridDim.x) {
        int gslot = g * 4 + wv;
        bool valid = gslot < count;
        int row = list[valid ? gslot : 0];

        // broadcast-load full row into registers
        float zr[64];
        {
            const float4* zp = (const float4*)(z + (size_t)row * DIM);
            #pragma unroll
            for (int q = 0; q < 16; ++q) {
                float4 t = zp[q];
                zr[q * 4 + 0] = t.x; zr[q * 4 + 1] = t.y;
                zr[q * 4 + 2] = t.z; zr[q * 4 + 3] = t.w;
            }
        }
        // norm with the same butterfly rounding as the argmin prologue
        float vlane = z[(size_t)row * DIM + lane];
        float s = vlane * vlane;
        #pragma unroll
        for (int off = 32; off > 0; off >>= 1) s += __shfl_xor(s, off);
        float denom = fmaxf(sqrtf(s), 1e-12f);
        #pragma unroll
        for (int d = 0; d < 64; ++d) zr[d] = zr[d] / denom;
        float znl = vlane / denom;
        float zsq = znl * znl;
        #pragma unroll
        for (int off = 32; off > 0; off >>= 1) zsq += __shfl_xor(zsq, off);

        float dmin = 3.4e38f;
        int kmin = 0;
        for (int t = 0; t < KCODES / 64; ++t) {
            {   // stage 64 codes into LDS, coalesced (thread: code tid>>2, seg tid&3)
                int c = tid >> 2, seg = tid & 3;
                const float4* src = (const float4*)(w + ((size_t)(t * 64 + c)) * DIM + seg * 16);
                float4 v0 = src[0], v1 = src[1], v2 = src[2], v3 = src[3];
                float4* dst = (float4*)(wt + c * 68 + seg * 16);
                dst[0] = v0; dst[1] = v1; dst[2] = v2; dst[3] = v3;
            }
            __syncthreads();
            int code = t * 64 + lane;
            const float* wp = wt + lane * 68;
            float acc = 0.f;
            #pragma unroll
            for (int d4 = 0; d4 < 16; ++d4) {
                float4 w4 = *(const float4*)(wp + d4 * 4);
                acc = fmaf(w4.x, zr[d4 * 4 + 0], acc);
                acc = fmaf(w4.y, zr[d4 * 4 + 1], acc);
                acc = fmaf(w4.z, zr[d4 * 4 + 2], acc);
                acc = fmaf(w4.w, zr[d4 * 4 + 3], acc);
            }
            float dist = (zsq - 2.0f * acc) + wsq[code];
            if (dist < dmin) { dmin = dist; kmin = code; }
            __syncthreads();
        }

        #pragma unroll
        for (int off = 1; off < 64; off <<= 1) {
            float d2 = __shfl_xor(dmin, off);
            int k2 = __shfl_xor(kmin, off);
            if (d2 < dmin || (d2 == dmin && k2 < kmin)) { dmin = d2; kmin = k2; }
        }
        if (lane == 0 && valid) {
            idx_ws[row] = kmin;
            idx_out[row] = (float)kmin;
        }
        __syncthreads();
    }
}

// ---------------- kernel E: gather z_q, loss partials, scatter EMA stats ----------------
__global__ void stats_kernel(const float* __restrict__ z,
                             const float* __restrict__ w,
                             const int* __restrict__ idx_ws,
                             float* __restrict__ zq_out,
                             float* __restrict__ bins,
                             float* __restrict__ esum,
                             float* __restrict__ loss_acc) {
    const int lane = threadIdx.x & 63;
    const int wv = threadIdx.x >> 6;
    const int gw = blockIdx.x * 4 + wv;
    const int nw = gridDim.x * 4;
    float lsum = 0.f;
    for (int row = gw; row < N_ROWS; row += nw) {
        float v = z[(size_t)row * DIM + lane];
        float s = v * v;
        #pragma unroll
        for (int off = 32; off > 0; off >>= 1) s += __shfl_xor(s, off);
        float zn = v / fmaxf(sqrtf(s), 1e-12f);
        int k = idx_ws[row];
        float wq = w[(size_t)k * DIM + lane];
        zq_out[(size_t)row * DIM + lane] = wq;
        float diff = wq - zn;
        lsum += diff * diff;
        atomicAdd(&esum[(size_t)k * DIM + lane], zn);
        if (lane == 0) atomicAdd(&bins[k], 1.0f);
    }
    __shared__ float red[256];
    red[threadIdx.x] = lsum;
    __syncthreads();
    for (int s = 128; s > 0; s >>= 1) {
        if (threadIdx.x < s) red[threadIdx.x] += red[threadIdx.x + s];
        __syncthreads();
    }
    if (threadIdx.x == 0) atomicAdd(loss_acc, red[0]);
}

// ---------------- kernel F: per-code EMA finalize + loss scalar ----------------
__global__ void finalize_kernel(const float* __restrict__ w,
                                const float* __restrict__ cs,
                                const float* __restrict__ ea,
                                const float* __restrict__ bins,
                                const float* __restrict__ esum,
                                const float* __restrict__ loss_acc,
                                float* __restrict__ out_cs,
                                float* __restrict__ out_ea,
                                float* __restrict__ out_w,
                                float* __restrict__ out_loss) {
    const int gid = blockIdx.x * blockDim.x + threadIdx.x;
    if (gid == 0) out_loss[0] = 0.25f * loss_acc[0] / 4194304.0f;
    const int k = gid >> 6;
    const int lane = threadIdx.x & 63;
    if (k >= KCODES) return;
    float b = bins[k];
    if (lane == 0) out_cs[k] = cs[k] * 0.99f + 0.01f * b;
    size_t off = (size_t)k * DIM + lane;
    float es = esum[off];
    out_ea[off] = ea[off] * 0.99f + 0.01f * es;
    float wv = w[off];
    float bc = (b == 0.0f) ? 1.0f : b;
    float t = es / bc;
    float s = t * t;
    #pragma unroll
    for (int o = 32; o > 0; o >>= 1) s += __shfl_xor(s, o);
    float en = t / fmaxf(sqrtf(s), 1e-12f);
    if (b == 0.0f) en = wv;
    float nw = wv * 0.99f + 0.01f * en;
    float s2 = nw * nw;
    #pragma unroll
    for (int o = 32; o > 0; o >>= 1) s2 += __shfl_xor(s2, o);
    out_w[off] = nw / fmaxf(sqrtf(s2), 1e-12f);
}

extern "C" void kernel_launch(void* const* d_in, const int* in_sizes, int n_in,
                              void* d_out, int out_size, void* d_ws, size_t ws_size,
                              hipStream_t stream) {
    const float* z  = (const float*)d_in[0];
    const float* w  = (const float*)d_in[1];
    const float* cs = (const float*)d_in[2];
    const float* ea = (const float*)d_in[3];

    float* out = (float*)d_out;
    float* out_zq   = out;                 // 4194304
    float* out_loss = out + 4194304;       // 1
    float* out_idx  = out + 4194305;       // 65536
    float* out_cs   = out + 4259841;       // 8192
    float* out_ea   = out + 4268033;       // 524288
    float* out_w    = out + 4792321;       // 524288

    // scratch inside z_q output region (fully rewritten by stats_kernel afterwards)
    unsigned short* whl = (unsigned short*)d_out;       // floats [0, 524288)
    int*   countp = (int*)(out + 524288);
    int*   list   = (int*)(out + 524289);
    float* pm1    = out + 1048576;
    float* pm2    = out + 1310720;
    int*   pk1    = (int*)(out + 1572864);

    float* ws = (float*)d_ws;
    float* wsq  = ws + WS_WSQ;
    int*   idxb = (int*)(ws + WS_IDX);
    float* bins = ws + WS_BINS;
    float* esum = ws + WS_ESUM;
    float* loss = ws + WS_LOSS;

    hipMemsetAsync(bins, 0, (size_t)(8192 + 524288 + 1) * sizeof(float), stream);
    hipMemsetAsync(countp, 0, sizeof(int), stream);

    prep_kernel<<<KCODES * 64 / 256, 256, 0, stream>>>(w, wsq, whl);
    argmin_mfma_kernel<<<(N_ROWS / 256) * KSPLIT, 256, 0, stream>>>(z, whl, pm1, pm2, pk1);
    merge_kernel<<<N_ROWS / 256, 256, 0, stream>>>(pm1, pm2, pk1, idxb, out_idx, countp, list);
    fallback_kernel<<<256, 256, 0, stream>>>(z, w, wsq, countp, list, idxb, out_idx);
    stats_kernel<<<512, 256, 0, stream>>>(z, w, idxb, out_zq, bins, esum, loss);
    finalize_kernel<<<KCODES * 64 / 256, 256, 0, stream>>>(w, cs, ea, bins, esum, loss,
                                                           out_cs, out_ea, out_w, out_loss);
}

// Round 4
// 428.859 us; speedup vs baseline: 2.4728x; 1.1399x over previous
//
#include <hip/hip_runtime.h>
#include <math.h>

#define N_ROWS 65536
#define KCODES 8192
#define DIM 64
#define MARGIN 3e-4f
#define KSPLIT 4
#define KPER (KCODES / KSPLIT)   // 2048
#define NROUNDS (KPER / 64)      // 32

// ws layout (floats) — proven footprint (606209 floats)
#define WS_WSQ   0          // 8192
#define WS_IDX   8192       // 65536 ints
#define WS_BINS  73728      // 8192
#define WS_ESUM  81920      // 524288
#define WS_LOSS  606208     // 1

// d_out scratch map (all regions rewritten by later kernels):
//   zn fp32:   out[0 .. 4194304)           (z_q region; stats overwrites with z_q)
//   count:     out[4194304]                (out_loss slot; finalize overwrites)
//   list:      out[4194305 .. 4259841)     (out_idx region; stats overwrites)
//   whl:       out[4268032 .. 4792320)     (cs-last + ea region; finalize overwrites; 16B-aligned)
//   pm1:       out[4792321 .. 5054465)     (out_w region; finalize overwrites)
//   pack:      out[5054465 .. 5316609)

typedef short short8 __attribute__((ext_vector_type(8)));
typedef float f32x4 __attribute__((ext_vector_type(4)));

#define MFMA_BF16(A, B, C) __builtin_amdgcn_mfma_f32_16x16x32_bf16(A, B, C, 0, 0, 0)

__device__ __forceinline__ unsigned short f2bf(float f) {
    unsigned u = __float_as_uint(f);
    unsigned r = u + 0x7FFFu + ((u >> 16) & 1u);   // RTNE
    return (unsigned short)(r >> 16);
}
__device__ __forceinline__ float b2f(unsigned short h) {
    return __uint_as_float(((unsigned)h) << 16);
}
__device__ __forceinline__ void gload16(const unsigned short* g, unsigned short* l) {
    __builtin_amdgcn_global_load_lds(
        (const __attribute__((address_space(1))) unsigned int*)g,
        (__attribute__((address_space(3))) unsigned int*)l, 16, 0, 0);
}

// ---------------- kernel A0: normalize z once ----------------
__global__ void prep_z_kernel(const float* __restrict__ z, float* __restrict__ zn) {
    const int lane = threadIdx.x & 63;
    const int wv = threadIdx.x >> 6;
    const int base = blockIdx.x * 64;
    for (int i = 0; i < 16; ++i) {
        int row = base + i * 4 + wv;
        float v = z[(size_t)row * DIM + lane];
        float s = v * v;
        #pragma unroll
        for (int off = 32; off > 0; off >>= 1) s += __shfl_xor(s, off);
        zn[(size_t)row * DIM + lane] = v / fmaxf(sqrtf(s), 1e-12f);
    }
}

// ---------------- kernel A1: per-code squared norms + bf16 hi/lo split ----------------
__global__ void prep_w_kernel(const float* __restrict__ w, float* __restrict__ wsq,
                              unsigned short* __restrict__ whl) {
    int wid = (blockIdx.x * blockDim.x + threadIdx.x) >> 6;
    int lane = threadIdx.x & 63;
    if (wid >= KCODES) return;
    float v = w[(size_t)wid * DIM + lane];
    float s = v * v;
    #pragma unroll
    for (int off = 32; off > 0; off >>= 1) s += __shfl_xor(s, off);
    if (lane == 0) wsq[wid] = s;
    unsigned short h = f2bf(v);
    unsigned short l = f2bf(v - b2f(h));
    whl[(size_t)wid * 128 + lane] = h;
    whl[(size_t)wid * 128 + 64 + lane] = l;
}

// ---------------- kernel B: K-split MFMA argmax-dot ----------------
// grid 2048 = 512 rowblocks(128 rows) x 4 k-quarters; 4 waves x 32 rows; 4 blocks/CU exact.
__launch_bounds__(256, 4)
__global__ void argmin_mfma_kernel(const float* __restrict__ zn,
                                   const unsigned short* __restrict__ whl,
                                   float* __restrict__ pm1,
                                   unsigned int* __restrict__ pack) {
    __shared__ unsigned short smem[16384];   // 2 x 16 KB B-tile buffers

    const int tid = threadIdx.x;
    const int lane = tid & 63;
    const int wv = tid >> 6;
    const int n_a = lane & 15;
    const int quad = lane >> 4;
    const int rowblk = blockIdx.x >> 2;
    const int kq = blockIdx.x & 3;
    const int kbase = kq * KPER;

    #define ISSUE_TILE(r, bdst)                                                  \
        {                                                                        \
            const size_t cg0 = (size_t)(kbase + (r) * 64);                       \
            _Pragma("unroll")                                                    \
            for (int i = 0; i < 4; ++i) {                                        \
                int slot = wv * 256 + i * 64 + lane;                             \
                int cl = slot >> 4;                                              \
                int jg = (slot & 15) ^ (cl & 15);                                \
                gload16(whl + (cg0 + cl) * 128 + jg * 8,                         \
                        (bdst) + wv * 2048 + i * 512);                           \
            }                                                                    \
        }

    ISSUE_TILE(0, smem);

    // A fragments: load zn directly, split to bf16 hi/lo in registers
    short8 a_h[2][2], a_l[2][2];
    #pragma unroll
    for (int mt = 0; mt < 2; ++mt) {
        int row = rowblk * 128 + wv * 32 + mt * 16 + n_a;
        #pragma unroll
        for (int ks = 0; ks < 2; ++ks) {
            const float* p = zn + (size_t)row * DIM + ks * 32 + quad * 8;
            float4 f0 = *(const float4*)p;
            float4 f1 = *(const float4*)(p + 4);
            float f[8] = {f0.x, f0.y, f0.z, f0.w, f1.x, f1.y, f1.z, f1.w};
            short8 vh, vl;
            #pragma unroll
            for (int j = 0; j < 8; ++j) {
                unsigned short h = f2bf(f[j]);
                unsigned short l = f2bf(f[j] - b2f(h));
                vh[j] = (short)h; vl[j] = (short)l;
            }
            a_h[mt][ks] = vh; a_l[mt][ks] = vl;
        }
    }

    float m1v[2][4], m2v[2][4];
    int kkv[2][4];
    #pragma unroll
    for (int mt = 0; mt < 2; ++mt)
        #pragma unroll
        for (int i = 0; i < 4; ++i) { m1v[mt][i] = -3.4e38f; m2v[mt][i] = -3.4e38f; kkv[mt][i] = 0; }

    __syncthreads();

    for (int r = 0; r < NROUNDS; ++r) {
        unsigned short* bc = smem + (r & 1) * 8192;
        if (r + 1 < NROUNDS) ISSUE_TILE(r + 1, smem + ((r + 1) & 1) * 8192);

        #pragma unroll
        for (int nt = 0; nt < 4; ++nt) {
            const int cl = nt * 16 + n_a;
            const unsigned short* bp = bc + cl * 128;
            short8 bh0 = *(const short8*)(bp + ((quad) ^ n_a) * 8);
            short8 bh1 = *(const short8*)(bp + ((4 + quad) ^ n_a) * 8);
            short8 bl0 = *(const short8*)(bp + ((8 + quad) ^ n_a) * 8);
            short8 bl1 = *(const short8*)(bp + ((12 + quad) ^ n_a) * 8);
            f32x4 acc[2];
            #pragma unroll
            for (int mt = 0; mt < 2; ++mt) {
                f32x4 a = {0.f, 0.f, 0.f, 0.f};
                a = MFMA_BF16(a_h[mt][0], bh0, a);
                a = MFMA_BF16(a_h[mt][1], bh1, a);
                a = MFMA_BF16(a_l[mt][0], bh0, a);
                a = MFMA_BF16(a_l[mt][1], bh1, a);
                a = MFMA_BF16(a_h[mt][0], bl0, a);
                a = MFMA_BF16(a_h[mt][1], bl1, a);
                acc[mt] = a;
            }
            const int c = kbase + r * 64 + nt * 16 + n_a;
            #pragma unroll
            for (int mt = 0; mt < 2; ++mt)
                #pragma unroll
                for (int i = 0; i < 4; ++i) {
                    float v = acc[mt][i];
                    m2v[mt][i] = __builtin_amdgcn_fmed3f(v, m1v[mt][i], m2v[mt][i]);
                    bool gt = v > m1v[mt][i];
                    kkv[mt][i] = gt ? c : kkv[mt][i];
                    m1v[mt][i] = fmaxf(m1v[mt][i], v);
                }
        }
        __syncthreads();
    }

    // reduce top-2 across the 16 col-lanes per row; write compressed partials
    #pragma unroll
    for (int mt = 0; mt < 2; ++mt)
        #pragma unroll
        for (int i = 0; i < 4; ++i) {
            float v1 = m1v[mt][i], v2 = m2v[mt][i];
            int k = kkv[mt][i];
            #pragma unroll
            for (int off = 1; off < 16; off <<= 1) {
                float o1 = __shfl_xor(v1, off);
                float o2 = __shfl_xor(v2, off);
                int ok = __shfl_xor(k, off);
                float lo = fminf(v1, o1);
                v2 = fmaxf(fmaxf(v2, o2), lo);
                bool take = (o1 > v1) || (o1 == v1 && ok < k);
                k = take ? ok : k;
                v1 = fmaxf(v1, o1);
            }
            if (n_a == 0) {
                int row_g = rowblk * 128 + wv * 32 + mt * 16 + quad * 4 + i;
                float gap = v1 - v2;                       // >= 0
                unsigned gb = __float_as_uint(gap) >> 16;  // truncate -> conservative
                pm1[row_g * 4 + kq] = v1;
                pack[row_g * 4 + kq] = (gb << 16) | (unsigned)k;
            }
        }
    #undef ISSUE_TILE
}

// ---------------- kernel C: merge 4 K-partials per row, flag close rows ----------------
__global__ void merge_kernel(const float* __restrict__ pm1, const unsigned int* __restrict__ pack,
                             int* __restrict__ idx_ws,
                             int* __restrict__ countp, int* __restrict__ list) {
    int row = blockIdx.x * blockDim.x + threadIdx.x;
    if (row >= N_ROWS) return;
    float v1 = -3.4e38f, v2 = -3.4e38f;
    int k1 = 0x7fffffff;
    #pragma unroll
    for (int kq = 0; kq < KSPLIT; ++kq) {
        float a1 = pm1[row * 4 + kq];
        unsigned p = pack[row * 4 + kq];
        int ak = (int)(p & 0xFFFFu);
        float a2 = a1 - b2f((unsigned short)(p >> 16));   // >= that quarter's true m2
        if (a1 > v1) { v2 = fmaxf(v1, a2); v1 = a1; k1 = ak; }
        else { v2 = fmaxf(v2, a1); if (a1 == v1 && ak < k1) k1 = ak; }
    }
    idx_ws[row] = k1;
    if (v1 - v2 < MARGIN) {
        int pos = atomicAdd(countp, 1);
        list[pos] = row;
    }
}

// ---------------- kernel D: exact fp32 re-rank, one wave per flagged row ----------------
__launch_bounds__(256, 2)
__global__ void fallback_kernel(const float* __restrict__ zn, const float* __restrict__ w,
                                const float* __restrict__ wsq,
                                const int* __restrict__ countp, const int* __restrict__ list,
                                int* __restrict__ idx_ws) {
    __shared__ float wt[64 * 68];
    const int tid = threadIdx.x;
    const int lane = tid & 63;
    const int wv = tid >> 6;
    const int count = *countp;
    const int ngroups = (count + 3) / 4;

    for (int g = blockIdx.x; g < ngroups; g += gridDim.x) {
        int gslot = g * 4 + wv;
        bool valid = gslot < count;
        int row = list[valid ? gslot : 0];

        float zr[64];
        {
            const float4* zp = (const float4*)(zn + (size_t)row * DIM);
            #pragma unroll
            for (int q = 0; q < 16; ++q) {
                float4 t = zp[q];
                zr[q * 4 + 0] = t.x; zr[q * 4 + 1] = t.y;
                zr[q * 4 + 2] = t.z; zr[q * 4 + 3] = t.w;
            }
        }
        float znl = zn[(size_t)row * DIM + lane];
        float zsq = znl * znl;
        #pragma unroll
        for (int off = 32; off > 0; off >>= 1) zsq += __shfl_xor(zsq, off);

        float dmin = 3.4e38f;
        int kmin = 0;
        for (int t = 0; t < KCODES / 64; ++t) {
            {
                int c = tid >> 2, seg = tid & 3;
                const float4* src = (const float4*)(w + ((size_t)(t * 64 + c)) * DIM + seg * 16);
                float4 v0 = src[0], v1 = src[1], v2 = src[2], v3 = src[3];
                float4* dst = (float4*)(wt + c * 68 + seg * 16);
                dst[0] = v0; dst[1] = v1; dst[2] = v2; dst[3] = v3;
            }
            __syncthreads();
            int code = t * 64 + lane;
            const float* wp = wt + lane * 68;
            float acc = 0.f;
            #pragma unroll
            for (int d4 = 0; d4 < 16; ++d4) {
                float4 w4 = *(const float4*)(wp + d4 * 4);
                acc = fmaf(w4.x, zr[d4 * 4 + 0], acc);
                acc = fmaf(w4.y, zr[d4 * 4 + 1], acc);
                acc = fmaf(w4.z, zr[d4 * 4 + 2], acc);
                acc = fmaf(w4.w, zr[d4 * 4 + 3], acc);
            }
            float dist = (zsq - 2.0f * acc) + wsq[code];
            if (dist < dmin) { dmin = dist; kmin = code; }
            __syncthreads();
        }

        #pragma unroll
        for (int off = 1; off < 64; off <<= 1) {
            float d2 = __shfl_xor(dmin, off);
            int k2 = __shfl_xor(kmin, off);
            if (d2 < dmin || (d2 == dmin && k2 < kmin)) { dmin = d2; kmin = k2; }
        }
        if (lane == 0 && valid) idx_ws[row] = kmin;
        __syncthreads();
    }
}

// ---------------- kernel E: gather z_q (over zn in-place), idx out, loss, EMA scatter ----------------
__global__ void stats_kernel(float* __restrict__ zq,              // holds zn on entry
                             const float* __restrict__ w,
                             const int* __restrict__ idx_ws,
                             float* __restrict__ idx_out,
                             float* __restrict__ bins,
                             float* __restrict__ esum,
                             float* __restrict__ loss_acc) {
    const int lane = threadIdx.x & 63;
    const int wv = threadIdx.x >> 6;
    const int gw = blockIdx.x * 4 + wv;
    const int nw = gridDim.x * 4;
    float lsum = 0.f;
    for (int row = gw; row < N_ROWS; row += nw) {
        float znv = zq[(size_t)row * DIM + lane];
        int k = idx_ws[row];
        float wq = w[(size_t)k * DIM + lane];
        zq[(size_t)row * DIM + lane] = wq;         // overwrite zn with z_q
        if (lane == 0) idx_out[row] = (float)k;
        float diff = wq - znv;
        lsum += diff * diff;
        atomicAdd(&esum[(size_t)k * DIM + lane], znv);
        if (lane == 0) atomicAdd(&bins[k], 1.0f);
    }
    __shared__ float red[256];
    red[threadIdx.x] = lsum;
    __syncthreads();
    for (int s = 128; s > 0; s >>= 1) {
        if (threadIdx.x < s) red[threadIdx.x] += red[threadIdx.x + s];
        __syncthreads();
    }
    if (threadIdx.x == 0) atomicAdd(loss_acc, red[0]);
}

// ---------------- kernel F: per-code EMA finalize + loss scalar ----------------
__global__ void finalize_kernel(const float* __restrict__ w,
                                const float* __restrict__ cs,
                                const float* __restrict__ ea,
                                const float* __restrict__ bins,
                                const float* __restrict__ esum,
                                const float* __restrict__ loss_acc,
                                float* __restrict__ out_cs,
                                float* __restrict__ out_ea,
                                float* __restrict__ out_w,
                                float* __restrict__ out_loss) {
    const int gid = blockIdx.x * blockDim.x + threadIdx.x;
    if (gid == 0) out_loss[0] = 0.25f * loss_acc[0] / 4194304.0f;
    const int k = gid >> 6;
    const int lane = threadIdx.x & 63;
    if (k >= KCODES) return;
    float b = bins[k];
    if (lane == 0) out_cs[k] = cs[k] * 0.99f + 0.01f * b;
    size_t off = (size_t)k * DIM + lane;
    float es = esum[off];
    out_ea[off] = ea[off] * 0.99f + 0.01f * es;
    float wv = w[off];
    float bc = (b == 0.0f) ? 1.0f : b;
    float t = es / bc;
    float s = t * t;
    #pragma unroll
    for (int o = 32; o > 0; o >>= 1) s += __shfl_xor(s, o);
    float en = t / fmaxf(sqrtf(s), 1e-12f);
    if (b == 0.0f) en = wv;
    float nw = wv * 0.99f + 0.01f * en;
    float s2 = nw * nw;
    #pragma unroll
    for (int o = 32; o > 0; o >>= 1) s2 += __shfl_xor(s2, o);
    out_w[off] = nw / fmaxf(sqrtf(s2), 1e-12f);
}

extern "C" void kernel_launch(void* const* d_in, const int* in_sizes, int n_in,
                              void* d_out, int out_size, void* d_ws, size_t ws_size,
                              hipStream_t stream) {
    const float* z  = (const float*)d_in[0];
    const float* w  = (const float*)d_in[1];
    const float* cs = (const float*)d_in[2];
    const float* ea = (const float*)d_in[3];

    float* out = (float*)d_out;
    float* out_zq   = out;                 // 4194304  (also zn scratch)
    float* out_loss = out + 4194304;       // 1        (also count scratch)
    float* out_idx  = out + 4194305;       // 65536    (also list scratch)
    float* out_cs   = out + 4259841;       // 8192
    float* out_ea   = out + 4268033;       // 524288
    float* out_w    = out + 4792321;       // 524288   (also pm1/pack scratch)

    float*          zn     = out_zq;
    int*            countp = (int*)(out + 4194304);
    int*            list   = (int*)(out + 4194305);
    unsigned short* whl    = (unsigned short*)(out + 4268032);   // 16B-aligned
    float*          pm1    = out + 4792321;
    unsigned int*   pack   = (unsigned int*)(out + 5054465);

    float* ws = (float*)d_ws;
    float* wsq  = ws + WS_WSQ;
    int*   idxb = (int*)(ws + WS_IDX);
    float* bins = ws + WS_BINS;
    float* esum = ws + WS_ESUM;
    float* loss = ws + WS_LOSS;

    hipMemsetAsync(bins, 0, (size_t)(8192 + 524288 + 1) * sizeof(float), stream);
    hipMemsetAsync(countp, 0, sizeof(int), stream);

    prep_z_kernel<<<N_ROWS / 64, 256, 0, stream>>>(z, zn);
    prep_w_kernel<<<KCODES * 64 / 256, 256, 0, stream>>>(w, wsq, whl);
    argmin_mfma_kernel<<<(N_ROWS / 128) * KSPLIT, 256, 0, stream>>>(zn, whl, pm1, pack);
    merge_kernel<<<N_ROWS / 256, 256, 0, stream>>>(pm1, pack, idxb, countp, list);
    fallback_kernel<<<256, 256, 0, stream>>>(zn, w, wsq, countp, list, idxb);
    stats_kernel<<<512, 256, 0, stream>>>(out_zq, w, idxb, out_idx, bins, esum, loss);
    finalize_kernel<<<KCODES * 64 / 256, 256, 0, stream>>>(w, cs, ea, bins, esum, loss,
                                                           out_cs, out_ea, out_w, out_loss);
}

// Round 5
// 351.385 us; speedup vs baseline: 3.0180x; 1.2205x over previous
//
#include <hip/hip_runtime.h>
#include <math.h>

#define N_ROWS 65536
#define KCODES 8192
#define DIM 64
#define MARGIN 1.25e-4f
#define KSPLIT 4
#define KPER (KCODES / KSPLIT)   // 2048
#define NROUNDS (KPER / 64)      // 32
#define LIST_CAP 32768

// ws layout (floats) — proven footprint (606209 floats)
#define WS_WSQ   0          // 8192
#define WS_IDX   8192       // 65536 ints
#define WS_BINS  73728      // 8192
#define WS_ESUM  81920      // 524288  (wT during fallback; esum memset after fallback)
#define WS_LOSS  606208     // 1

// d_out scratch map (all regions rewritten by later kernels):
//   zn fp32:   out[0 .. 4194304)           (z_q region; stats overwrites with z_q)
//   count:     out[4194304]                (out_loss slot; finalize overwrites)
//   list:      out[4194305 .. 4259841)     (out_idx region; stats overwrites)
//   whl:       out[4268032 .. 4792320)     (cs-last + ea region; finalize overwrites)
//   pm1/fbmin: out[4792321 .. 5054465)     (out_w region; finalize overwrites)
//   pack/fbk:  out[5054465 .. 5316609)

typedef short short8 __attribute__((ext_vector_type(8)));
typedef float f32x4 __attribute__((ext_vector_type(4)));

#define MFMA_BF16(A, B, C) __builtin_amdgcn_mfma_f32_16x16x32_bf16(A, B, C, 0, 0, 0)

__device__ __forceinline__ unsigned short f2bf(float f) {
    unsigned u = __float_as_uint(f);
    unsigned r = u + 0x7FFFu + ((u >> 16) & 1u);   // RTNE
    return (unsigned short)(r >> 16);
}
__device__ __forceinline__ float b2f(unsigned short h) {
    return __uint_as_float(((unsigned)h) << 16);
}
__device__ __forceinline__ void gload16(const unsigned short* g, unsigned short* l) {
    __builtin_amdgcn_global_load_lds(
        (const __attribute__((address_space(1))) unsigned int*)g,
        (__attribute__((address_space(3))) unsigned int*)l, 16, 0, 0);
}

// ---------------- kernel A0: normalize z once ----------------
__global__ void prep_z_kernel(const float* __restrict__ z, float* __restrict__ zn) {
    const int lane = threadIdx.x & 63;
    const int wv = threadIdx.x >> 6;
    const int base = blockIdx.x * 64;
    for (int i = 0; i < 16; ++i) {
        int row = base + i * 4 + wv;
        float v = z[(size_t)row * DIM + lane];
        float s = v * v;
        #pragma unroll
        for (int off = 32; off > 0; off >>= 1) s += __shfl_xor(s, off);
        zn[(size_t)row * DIM + lane] = v / fmaxf(sqrtf(s), 1e-12f);
    }
}

// ---------------- kernel A1: per-code squared norms + bf16 hi/lo split ----------------
__global__ void prep_w_kernel(const float* __restrict__ w, float* __restrict__ wsq,
                              unsigned short* __restrict__ whl) {
    int wid = (blockIdx.x * blockDim.x + threadIdx.x) >> 6;
    int lane = threadIdx.x & 63;
    if (wid >= KCODES) return;
    float v = w[(size_t)wid * DIM + lane];
    float s = v * v;
    #pragma unroll
    for (int off = 32; off > 0; off >>= 1) s += __shfl_xor(s, off);
    if (lane == 0) wsq[wid] = s;
    unsigned short h = f2bf(v);
    unsigned short l = f2bf(v - b2f(h));
    whl[(size_t)wid * 128 + lane] = h;
    whl[(size_t)wid * 128 + 64 + lane] = l;
}

// ---------------- kernel A2: transpose w -> wT[d][k] (coalesced fallback reads) ----------------
__global__ void prep_wT_kernel(const float* __restrict__ w, float* __restrict__ wT) {
    __shared__ float tile[64 * 65];
    const int t = threadIdx.x;
    const int c0 = blockIdx.x * 64;
    #pragma unroll
    for (int i = 0; i < 16; ++i) {
        int idx = i * 256 + t;
        int c = idx >> 6, d = idx & 63;
        tile[c * 65 + d] = w[(size_t)(c0 + c) * DIM + d];
    }
    __syncthreads();
    #pragma unroll
    for (int i = 0; i < 16; ++i) {
        int idx = i * 256 + t;
        int d = idx >> 6, c = idx & 63;
        wT[(size_t)d * KCODES + c0 + c] = tile[c * 65 + d];
    }
}

// ---------------- kernel B: K-split MFMA argmax-dot (unchanged from R4) ----------------
__launch_bounds__(256, 4)
__global__ void argmin_mfma_kernel(const float* __restrict__ zn,
                                   const unsigned short* __restrict__ whl,
                                   float* __restrict__ pm1,
                                   unsigned int* __restrict__ pack) {
    __shared__ unsigned short smem[16384];

    const int tid = threadIdx.x;
    const int lane = tid & 63;
    const int wv = tid >> 6;
    const int n_a = lane & 15;
    const int quad = lane >> 4;
    const int rowblk = blockIdx.x >> 2;
    const int kq = blockIdx.x & 3;
    const int kbase = kq * KPER;

    #define ISSUE_TILE(r, bdst)                                                  \
        {                                                                        \
            const size_t cg0 = (size_t)(kbase + (r) * 64);                       \
            _Pragma("unroll")                                                    \
            for (int i = 0; i < 4; ++i) {                                        \
                int slot = wv * 256 + i * 64 + lane;                             \
                int cl = slot >> 4;                                              \
                int jg = (slot & 15) ^ (cl & 15);                                \
                gload16(whl + (cg0 + cl) * 128 + jg * 8,                         \
                        (bdst) + wv * 2048 + i * 512);                           \
            }                                                                    \
        }

    ISSUE_TILE(0, smem);

    short8 a_h[2][2], a_l[2][2];
    #pragma unroll
    for (int mt = 0; mt < 2; ++mt) {
        int row = rowblk * 128 + wv * 32 + mt * 16 + n_a;
        #pragma unroll
        for (int ks = 0; ks < 2; ++ks) {
            const float* p = zn + (size_t)row * DIM + ks * 32 + quad * 8;
            float4 f0 = *(const float4*)p;
            float4 f1 = *(const float4*)(p + 4);
            float f[8] = {f0.x, f0.y, f0.z, f0.w, f1.x, f1.y, f1.z, f1.w};
            short8 vh, vl;
            #pragma unroll
            for (int j = 0; j < 8; ++j) {
                unsigned short h = f2bf(f[j]);
                unsigned short l = f2bf(f[j] - b2f(h));
                vh[j] = (short)h; vl[j] = (short)l;
            }
            a_h[mt][ks] = vh; a_l[mt][ks] = vl;
        }
    }

    float m1v[2][4], m2v[2][4];
    int kkv[2][4];
    #pragma unroll
    for (int mt = 0; mt < 2; ++mt)
        #pragma unroll
        for (int i = 0; i < 4; ++i) { m1v[mt][i] = -3.4e38f; m2v[mt][i] = -3.4e38f; kkv[mt][i] = 0; }

    __syncthreads();

    for (int r = 0; r < NROUNDS; ++r) {
        unsigned short* bc = smem + (r & 1) * 8192;
        if (r + 1 < NROUNDS) ISSUE_TILE(r + 1, smem + ((r + 1) & 1) * 8192);

        #pragma unroll
        for (int nt = 0; nt < 4; ++nt) {
            const int cl = nt * 16 + n_a;
            const unsigned short* bp = bc + cl * 128;
            short8 bh0 = *(const short8*)(bp + ((quad) ^ n_a) * 8);
            short8 bh1 = *(const short8*)(bp + ((4 + quad) ^ n_a) * 8);
            short8 bl0 = *(const short8*)(bp + ((8 + quad) ^ n_a) * 8);
            short8 bl1 = *(const short8*)(bp + ((12 + quad) ^ n_a) * 8);
            f32x4 acc[2];
            #pragma unroll
            for (int mt = 0; mt < 2; ++mt) {
                f32x4 a = {0.f, 0.f, 0.f, 0.f};
                a = MFMA_BF16(a_h[mt][0], bh0, a);
                a = MFMA_BF16(a_h[mt][1], bh1, a);
                a = MFMA_BF16(a_l[mt][0], bh0, a);
                a = MFMA_BF16(a_l[mt][1], bh1, a);
                a = MFMA_BF16(a_h[mt][0], bl0, a);
                a = MFMA_BF16(a_h[mt][1], bl1, a);
                acc[mt] = a;
            }
            const int c = kbase + r * 64 + nt * 16 + n_a;
            #pragma unroll
            for (int mt = 0; mt < 2; ++mt)
                #pragma unroll
                for (int i = 0; i < 4; ++i) {
                    float v = acc[mt][i];
                    m2v[mt][i] = __builtin_amdgcn_fmed3f(v, m1v[mt][i], m2v[mt][i]);
                    bool gt = v > m1v[mt][i];
                    kkv[mt][i] = gt ? c : kkv[mt][i];
                    m1v[mt][i] = fmaxf(m1v[mt][i], v);
                }
        }
        __syncthreads();
    }

    #pragma unroll
    for (int mt = 0; mt < 2; ++mt)
        #pragma unroll
        for (int i = 0; i < 4; ++i) {
            float v1 = m1v[mt][i], v2 = m2v[mt][i];
            int k = kkv[mt][i];
            #pragma unroll
            for (int off = 1; off < 16; off <<= 1) {
                float o1 = __shfl_xor(v1, off);
                float o2 = __shfl_xor(v2, off);
                int ok = __shfl_xor(k, off);
                float lo = fminf(v1, o1);
                v2 = fmaxf(fmaxf(v2, o2), lo);
                bool take = (o1 > v1) || (o1 == v1 && ok < k);
                k = take ? ok : k;
                v1 = fmaxf(v1, o1);
            }
            if (n_a == 0) {
                int row_g = rowblk * 128 + wv * 32 + mt * 16 + quad * 4 + i;
                float gap = v1 - v2;
                unsigned gb = __float_as_uint(gap) >> 16;  // truncate -> conservative
                pm1[row_g * 4 + kq] = v1;
                pack[row_g * 4 + kq] = (gb << 16) | (unsigned)k;
            }
        }
    #undef ISSUE_TILE
}

// ---------------- kernel C: merge 4 K-partials per row, flag close rows ----------------
__global__ void merge_kernel(const float* __restrict__ pm1, const unsigned int* __restrict__ pack,
                             int* __restrict__ idx_ws,
                             int* __restrict__ countp, int* __restrict__ list) {
    int row = blockIdx.x * blockDim.x + threadIdx.x;
    if (row >= N_ROWS) return;
    float v1 = -3.4e38f, v2 = -3.4e38f;
    int k1 = 0x7fffffff;
    #pragma unroll
    for (int kq = 0; kq < KSPLIT; ++kq) {
        float a1 = pm1[row * 4 + kq];
        unsigned p = pack[row * 4 + kq];
        int ak = (int)(p & 0xFFFFu);
        float a2 = a1 - b2f((unsigned short)(p >> 16));
        if (a1 > v1) { v2 = fmaxf(v1, a2); v1 = a1; k1 = ak; }
        else { v2 = fmaxf(v2, a1); if (a1 == v1 && ak < k1) k1 = ak; }
    }
    idx_ws[row] = k1;
    if (v1 - v2 < MARGIN) {
        int pos = atomicAdd(countp, 1);
        if (pos < LIST_CAP) list[pos] = row;
    }
}

// ---------------- kernel D: exact fp32 re-rank, parallel over (slot x code-chunk) ----------------
// unit = (slot, chunk of 1024 codes); 256 thr x 4 codes; coalesced wT reads.
__launch_bounds__(256, 4)
__global__ void fallback_kernel(const float* __restrict__ zn, const float* __restrict__ wT,
                                const float* __restrict__ wsq,
                                const int* __restrict__ countp, const int* __restrict__ list,
                                float* __restrict__ fbmin, int* __restrict__ fbk) {
    __shared__ float zr_s[64];
    __shared__ float zsq_s;
    __shared__ float wmin_s[4];
    __shared__ int wk_s[4];

    const int t = threadIdx.x;
    const int lane = t & 63;
    const int wv = t >> 6;
    const int count = min(*countp, LIST_CAP);
    const int nunits = count * 8;

    for (int bi = blockIdx.x; bi < nunits; bi += gridDim.x) {
        const int slot = bi >> 3;
        const int chunk = bi & 7;
        const int row = list[slot];

        __syncthreads();   // protect LDS reuse across grid-stride iterations
        if (t < 64) {
            float v = zn[(size_t)row * DIM + t];
            zr_s[t] = v;
            float q = v * v;
            #pragma unroll
            for (int off = 32; off > 0; off >>= 1) q += __shfl_xor(q, off);
            if (t == 0) zsq_s = q;
        }
        __syncthreads();

        float acc0 = 0.f, acc1 = 0.f, acc2 = 0.f, acc3 = 0.f;
        const float* wTp = wT + chunk * 1024 + t;
        #pragma unroll 8
        for (int d = 0; d < 64; ++d) {
            float zd = zr_s[d];
            const float* p = wTp + (size_t)d * KCODES;
            acc0 = fmaf(zd, p[0], acc0);
            acc1 = fmaf(zd, p[256], acc1);
            acc2 = fmaf(zd, p[512], acc2);
            acc3 = fmaf(zd, p[768], acc3);
        }

        float zq2 = zsq_s;
        float dmin = 3.4e38f;
        int kmin = 0;
        float a[4] = {acc0, acc1, acc2, acc3};
        #pragma unroll
        for (int j = 0; j < 4; ++j) {
            int c = chunk * 1024 + j * 256 + t;
            float dist = (zq2 - 2.0f * a[j]) + wsq[c];
            if (dist < dmin) { dmin = dist; kmin = c; }
        }
        #pragma unroll
        for (int off = 1; off < 64; off <<= 1) {
            float d2 = __shfl_xor(dmin, off);
            int k2 = __shfl_xor(kmin, off);
            if (d2 < dmin || (d2 == dmin && k2 < kmin)) { dmin = d2; kmin = k2; }
        }
        if (lane == 0) { wmin_s[wv] = dmin; wk_s[wv] = kmin; }
        __syncthreads();
        if (t == 0) {
            float dv = wmin_s[0]; int kv = wk_s[0];
            #pragma unroll
            for (int i = 1; i < 4; ++i) {
                float d2 = wmin_s[i]; int k2 = wk_s[i];
                if (d2 < dv || (d2 == dv && k2 < kv)) { dv = d2; kv = k2; }
            }
            fbmin[bi] = dv;
            fbk[bi] = kv;
        }
    }
}

// ---------------- kernel D2: merge 8 chunk partials per flagged row ----------------
__global__ void merge2_kernel(const float* __restrict__ fbmin, const int* __restrict__ fbk,
                              const int* __restrict__ countp, const int* __restrict__ list,
                              int* __restrict__ idx_ws) {
    int slot = blockIdx.x * blockDim.x + threadIdx.x;
    int count = min(*countp, LIST_CAP);
    if (slot >= count) return;
    float dv = 3.4e38f;
    int kv = 0;
    #pragma unroll
    for (int c = 0; c < 8; ++c) {
        float d2 = fbmin[slot * 8 + c];
        int k2 = fbk[slot * 8 + c];
        if (d2 < dv || (d2 == dv && k2 < kv)) { dv = d2; kv = k2; }
    }
    idx_ws[list[slot]] = kv;
}

// ---------------- kernel E: gather z_q (over zn in-place), idx out, loss, EMA scatter ----------------
__global__ void stats_kernel(float* __restrict__ zq,              // holds zn on entry
                             const float* __restrict__ w,
                             const int* __restrict__ idx_ws,
                             float* __restrict__ idx_out,
                             float* __restrict__ bins,
                             float* __restrict__ esum,
                             float* __restrict__ loss_acc) {
    const int lane = threadIdx.x & 63;
    const int wv = threadIdx.x >> 6;
    const int gw = blockIdx.x * 4 + wv;
    const int nw = gridDim.x * 4;
    float lsum = 0.f;
    for (int row = gw; row < N_ROWS; row += nw) {
        float znv = zq[(size_t)row * DIM + lane];
        int k = idx_ws[row];
        float wq = w[(size_t)k * DIM + lane];
        zq[(size_t)row * DIM + lane] = wq;
        if (lane == 0) idx_out[row] = (float)k;
        float diff = wq - znv;
        lsum += diff * diff;
        atomicAdd(&esum[(size_t)k * DIM + lane], znv);
        if (lane == 0) atomicAdd(&bins[k], 1.0f);
    }
    __shared__ float red[256];
    red[threadIdx.x] = lsum;
    __syncthreads();
    for (int s = 128; s > 0; s >>= 1) {
        if (threadIdx.x < s) red[threadIdx.x] += red[threadIdx.x + s];
        __syncthreads();
    }
    if (threadIdx.x == 0) atomicAdd(loss_acc, red[0]);
}

// ---------------- kernel F: per-code EMA finalize + loss scalar ----------------
__global__ void finalize_kernel(const float* __restrict__ w,
                                const float* __restrict__ cs,
                                const float* __restrict__ ea,
                                const float* __restrict__ bins,
                                const float* __restrict__ esum,
                                const float* __restrict__ loss_acc,
                                float* __restrict__ out_cs,
                                float* __restrict__ out_ea,
                                float* __restrict__ out_w,
                                float* __restrict__ out_loss) {
    const int gid = blockIdx.x * blockDim.x + threadIdx.x;
    if (gid == 0) out_loss[0] = 0.25f * loss_acc[0] / 4194304.0f;
    const int k = gid >> 6;
    const int lane = threadIdx.x & 63;
    if (k >= KCODES) return;
    float b = bins[k];
    if (lane == 0) out_cs[k] = cs[k] * 0.99f + 0.01f * b;
    size_t off = (size_t)k * DIM + lane;
    float es = esum[off];
    out_ea[off] = ea[off] * 0.99f + 0.01f * es;
    float wv = w[off];
    float bc = (b == 0.0f) ? 1.0f : b;
    float t = es / bc;
    float s = t * t;
    #pragma unroll
    for (int o = 32; o > 0; o >>= 1) s += __shfl_xor(s, o);
    float en = t / fmaxf(sqrtf(s), 1e-12f);
    if (b == 0.0f) en = wv;
    float nw = wv * 0.99f + 0.01f * en;
    float s2 = nw * nw;
    #pragma unroll
    for (int o = 32; o > 0; o >>= 1) s2 += __shfl_xor(s2, o);
    out_w[off] = nw / fmaxf(sqrtf(s2), 1e-12f);
}

extern "C" void kernel_launch(void* const* d_in, const int* in_sizes, int n_in,
                              void* d_out, int out_size, void* d_ws, size_t ws_size,
                              hipStream_t stream) {
    const float* z  = (const float*)d_in[0];
    const float* w  = (const float*)d_in[1];
    const float* cs = (const float*)d_in[2];
    const float* ea = (const float*)d_in[3];

    float* out = (float*)d_out;
    float* out_zq   = out;                 // 4194304  (zn scratch)
    float* out_loss = out + 4194304;       // 1        (count scratch)
    float* out_idx  = out + 4194305;       // 65536    (list scratch)
    float* out_cs   = out + 4259841;       // 8192
    float* out_ea   = out + 4268033;       // 524288
    float* out_w    = out + 4792321;       // 524288   (pm1/fbmin + pack/fbk scratch)

    float*          zn     = out_zq;
    int*            countp = (int*)(out + 4194304);
    int*            list   = (int*)(out + 4194305);
    unsigned short* whl    = (unsigned short*)(out + 4268032);   // 16B-aligned
    float*          pm1    = out + 4792321;
    unsigned int*   pack   = (unsigned int*)(out + 5054465);
    float*          fbmin  = pm1;                                // reuse after merge
    int*            fbk    = (int*)pack;

    float* ws = (float*)d_ws;
    float* wsq  = ws + WS_WSQ;
    int*   idxb = (int*)(ws + WS_IDX);
    float* bins = ws + WS_BINS;
    float* esum = ws + WS_ESUM;
    float* wT   = ws + WS_ESUM;            // wT lives here until esum memset
    float* loss = ws + WS_LOSS;

    hipMemsetAsync(bins, 0, (size_t)8192 * sizeof(float), stream);
    hipMemsetAsync(loss, 0, sizeof(float), stream);
    hipMemsetAsync(countp, 0, sizeof(int), stream);

    prep_z_kernel<<<N_ROWS / 64, 256, 0, stream>>>(z, zn);
    prep_w_kernel<<<KCODES * 64 / 256, 256, 0, stream>>>(w, wsq, whl);
    prep_wT_kernel<<<KCODES / 64, 256, 0, stream>>>(w, wT);
    argmin_mfma_kernel<<<(N_ROWS / 128) * KSPLIT, 256, 0, stream>>>(zn, whl, pm1, pack);
    merge_kernel<<<N_ROWS / 256, 256, 0, stream>>>(pm1, pack, idxb, countp, list);
    fallback_kernel<<<2048, 256, 0, stream>>>(zn, wT, wsq, countp, list, fbmin, fbk);
    merge2_kernel<<<256, 256, 0, stream>>>(fbmin, fbk, countp, list, idxb);
    // wT no longer needed; zero esum (same region) for the scatter
    hipMemsetAsync(esum, 0, (size_t)524288 * sizeof(float), stream);
    stats_kernel<<<512, 256, 0, stream>>>(out_zq, w, idxb, out_idx, bins, esum, loss);
    finalize_kernel<<<KCODES * 64 / 256, 256, 0, stream>>>(w, cs, ea, bins, esum, loss,
                                                           out_cs, out_ea, out_w, out_loss);
}